// Round 9
// baseline (152.451 us; speedup 1.0000x reference)
//
#include <hip/hip_runtime.h>

#define B_   2
#define C_   256
#define N_   4096
#define H_   8
#define HD_  32
#define G_   8
#define CPG_ 32

typedef short short8 __attribute__((ext_vector_type(8)));
typedef short short4v __attribute__((ext_vector_type(4)));
typedef unsigned uint4v __attribute__((ext_vector_type(4)));
typedef float f32x4  __attribute__((ext_vector_type(4)));
typedef float f4     __attribute__((ext_vector_type(4)));

__device__ __forceinline__ float b2f(short s) {
    return __uint_as_float(((unsigned)(unsigned short)s) << 16);
}
__device__ __forceinline__ short f2b(float f) {
    unsigned u = __float_as_uint(f);
    unsigned r = (u + 0x7FFF + ((u >> 16) & 1)) >> 16;  // RNE
    return (short)r;
}

// ---------------- Node 1: GN partial sums + W bf16 conversion (1152 blocks) ----------------
__global__ __launch_bounds__(256) void prep(const float* __restrict__ x,
                                            float* __restrict__ part,
                                            const float* __restrict__ wq,
                                            const float* __restrict__ wk,
                                            const float* __restrict__ wv,
                                            const float* __restrict__ wo,
                                            short* __restrict__ wb) {
    int blk = blockIdx.x;
    if (blk < 1024) {
        const f4* p = (const f4*)x + (size_t)(blk >> 6) * (CPG_ * N_ / 4) + (size_t)(blk & 63) * 512;
        float s = 0.f, ss = 0.f;
#pragma unroll
        for (int i = 0; i < 2; i++) {
            f4 v = p[threadIdx.x + i * 256];
#pragma unroll
            for (int j = 0; j < 4; j++) { float f = v[j]; s += f; ss += f * f; }
        }
#pragma unroll
        for (int off = 32; off > 0; off >>= 1) {
            s  += __shfl_down(s, off);
            ss += __shfl_down(ss, off);
        }
        __shared__ float rs[4], rss[4];
        int w = threadIdx.x >> 6;
        if ((threadIdx.x & 63) == 0) { rs[w] = s; rss[w] = ss; }
        __syncthreads();
        if (threadIdx.x == 0) {
            part[blk * 2]     = rs[0] + rs[1] + rs[2] + rs[3];
            part[blk * 2 + 1] = rss[0] + rss[1] + rss[2] + rss[3];
        }
    } else {
        int gid = (blk - 1024) * 256 + threadIdx.x;    // 0..32767
        int rid = gid >> 13;                           // 0..3
        int off = (gid & 8191) * 8;
        const float* src = rid == 0 ? wq : (rid == 1 ? wk : (rid == 2 ? wv : wo));
        f4 a = *(const f4*)(src + off);
        f4 b = *(const f4*)(src + off + 4);
        short8 r;
#pragma unroll
        for (int j = 0; j < 4; j++) { r[j] = f2b(a[j]); r[j + 4] = f2b(b[j]); }
        *(short8*)&wb[(size_t)rid * 65536 + off] = r;
    }
}

// ---------------- Node 2: QKV GEMM v3 — full 768-row W panel, x read ONCE ----------------
// 256 blocks (1/CU) x 512 threads. Block = (b, 32-n columns) x all 768 stacked outputs
// [wq|wk|wv]. x staged+GN'd exactly once (33.6 MB total, was 134). W tile (768x32 bf16,
// 61 KB LDS) restaged per k-step from L2. Per wave: 6 o-frags x 2 n-frags, 12 MFMA/k-step.
// Operand order per frag (Q/K: mfma(x,W); V: mfma(W,x)) matches the proven R8 epilogues.
__global__ __launch_bounds__(512) void gemm_qkv(
    const float* __restrict__ x,
    const float* __restrict__ gw, const float* __restrict__ gb,
    const float* __restrict__ part,
    const short* __restrict__ wb,
    const float* __restrict__ bq, const float* __restrict__ bk,
    const float* __restrict__ bv,
    short* __restrict__ q, short* __restrict__ kt, short* __restrict__ v) {
    int b = blockIdx.y;
    int n0 = blockIdx.x * 32;
    const float mul = 0.17677669529663687f * 1.4426950408889634f;

    __shared__ short wl[768][40];      // 61440 B
    __shared__ short xl[32][40];       // 2560 B
    __shared__ float mus[8], rstds[8];

    int tid = threadIdx.x, w = tid >> 6, lane = tid & 63, li = lane & 15, quad = lane >> 4;

    // GN stats: wave w reduces group w from part[]
    {
        const float* pp = &part[(size_t)(b * 8 + w) * 128 + lane * 2];
        float s = pp[0], ss = pp[1];
#pragma unroll
        for (int off = 32; off > 0; off >>= 1) {
            s  += __shfl_down(s, off);
            ss += __shfl_down(ss, off);
        }
        if (lane == 0) {
            const float inv = 1.f / (float)(CPG_ * N_);
            float mu = s * inv;
            float var = ss * inv - mu * mu;
            mus[w] = mu;
            rstds[w] = rsqrtf(var + 1e-5f);
        }
    }
    __syncthreads();

    f32x4 acc[6][2];
#pragma unroll
    for (int i = 0; i < 6; i++)
#pragma unroll
        for (int j = 0; j < 2; j++) acc[i][j] = (f32x4){0.f, 0.f, 0.f, 0.f};

    int cpair = tid >> 5, ln = tid & 31;    // x staging: 16 channel-pairs x 32 n
    int OW = w * 96;

    for (int k0 = 0; k0 < 256; k0 += 32) {
        // stage W: 768 rows x 32 k bf16, 6 short8 chunks/thread
#pragma unroll
        for (int s = 0; s < 6; s++) {
            int id = tid + 512 * s;
            int row = id >> 2, kc = (id & 3) << 3;
            *(short8*)&wl[row][kc] = *(const short8*)&wb[(size_t)row * 256 + k0 + kc];
        }
        // stage X with GN on the fly (b32 channel-pair writes)
        {
            int c0 = k0 + cpair * 2;
            int g0 = c0 >> 5;
            float rs_ = rstds[g0], mu_ = mus[g0];
            float a0 = rs_ * gw[c0],     b0 = gb[c0]     - mu_ * a0;
            float a1 = rs_ * gw[c0 + 1], b1 = gb[c0 + 1] - mu_ * a1;
            float v0 = x[((size_t)(b * 256 + c0)) * N_ + n0 + ln] * a0 + b0;
            float v1 = x[((size_t)(b * 256 + c0 + 1)) * N_ + n0 + ln] * a1 + b1;
            unsigned pk = (unsigned)(unsigned short)f2b(v0) |
                          ((unsigned)(unsigned short)f2b(v1) << 16);
            *(unsigned*)&xl[ln][cpair * 2] = pk;
        }
        __syncthreads();

        short8 xf0 = *(short8*)&xl[li][quad * 8];
        short8 xf1 = *(short8*)&xl[16 + li][quad * 8];
#pragma unroll
        for (int i = 0; i < 6; i++) {
            short8 wf = *(short8*)&wl[OW + i * 16 + li][quad * 8];
            if (OW + 16 * i < 512) {   // Q/K: output rows <-> n
                acc[i][0] = __builtin_amdgcn_mfma_f32_16x16x32_bf16(xf0, wf, acc[i][0], 0, 0, 0);
                acc[i][1] = __builtin_amdgcn_mfma_f32_16x16x32_bf16(xf1, wf, acc[i][1], 0, 0, 0);
            } else {                   // V: output rows <-> o
                acc[i][0] = __builtin_amdgcn_mfma_f32_16x16x32_bf16(wf, xf0, acc[i][0], 0, 0, 0);
                acc[i][1] = __builtin_amdgcn_mfma_f32_16x16x32_bf16(wf, xf1, acc[i][1], 0, 0, 0);
            }
        }
        __syncthreads();
    }

    // epilogues (index math from the proven R8 kernel)
#pragma unroll
    for (int i = 0; i < 6; i++) {
        int ob = OW + i * 16;
        int m = ob >> 8, om = ob & 255;
        if (m == 0) {          // Q^T [b][n][c], scaled
            short* outp = q + (size_t)b * N_ * C_;
            int o_ = om + li;
            float bv_ = bq[o_];
#pragma unroll
            for (int j = 0; j < 2; j++) {
                int nb_ = n0 + j * 16 + quad * 4;
#pragma unroll
                for (int r = 0; r < 4; r++)
                    outp[(size_t)(nb_ + r) * C_ + o_] = f2b((acc[i][j][r] + bv_) * mul);
            }
        } else if (m == 1) {   // K packed [b*8+h][m][32]
            int o_ = om + li;
            int hh = o_ >> 5, d = o_ & 31;
            float bv_ = bk[o_];
            short* kdst = kt + ((size_t)(b * 8 + hh) * N_) * HD_ + d;
#pragma unroll
            for (int j = 0; j < 2; j++) {
                int nb_ = n0 + j * 16 + quad * 4;
#pragma unroll
                for (int r = 0; r < 4; r++)
                    kdst[(size_t)(nb_ + r) * HD_] = f2b(acc[i][j][r] + bv_);
            }
        } else {               // V [b][c][n]
            short* outp = v + (size_t)b * C_ * N_;
            int obv = om + quad * 4;
#pragma unroll
            for (int j = 0; j < 2; j++) {
                int n_ = n0 + j * 16 + li;
#pragma unroll
                for (int r = 0; r < 4; r++)
                    outp[(size_t)(obv + r) * N_ + n_] = f2b(acc[i][j][r] + bv[obv + r]);
            }
        }
    }
}

// ---------------- Node 3: flash v18 — v14 body, SP=1, fused normalize -> bf16 aoT ----------------
__global__ __launch_bounds__(512) void flash(const short* __restrict__ q,
                                             const short* __restrict__ ktp,
                                             const short* __restrict__ v,
                                             short* __restrict__ aoT) {
    int bid = blockIdx.x;          // 0..255
    int xcd = bid & 7;
    int rest = bid >> 3;           // 0..31
    int bh = xcd * 2 + (rest & 1);
    int nb = rest >> 1;            // 0..15 -> 256 rows each
    int b = bh >> 3, h = bh & 7;

    const short* QT = q   + (size_t)b * N_ * C_ + h * HD_;
    const short* KP = ktp + (size_t)bh * N_ * HD_;
    const short* V  = v   + ((size_t)b * C_ + h * HD_) * N_;
    short* O = aoT + (size_t)b * N_ * C_ + h * HD_;

    __shared__ short kl[2 * 2560];   // K tile: 64 m-rows x 32 d, stride 40
    __shared__ short vl[2 * 2304];   // V tile: 32 d-rows x 64 slots, stride 72 (slot-permuted)

    int tid = threadIdx.x, w = tid >> 6, lane = tid & 63, li = lane & 15, quad = lane >> 4;
    int n0w = nb * 256 + w * 32;     // 8 waves x 32 rows

    short8 qf0 = *(const short8*)&QT[(size_t)(n0w + li) * 256 + quad * 8];
    short8 qf1 = *(const short8*)&QT[(size_t)(n0w + 16 + li) * 256 + quad * 8];

    f32x4 oa00 = (f32x4){0.f,0.f,0.f,0.f}, oa01 = oa00, oa10 = oa00, oa11 = oa00;
    float lr0 = 0.f, lr1 = 0.f;
    const f32x4 zero = (f32x4){0.f, 0.f, 0.f, 0.f};

    int krow = tid >> 3, kcol = (tid & 7) << 2;
    const short* kgp = KP + (size_t)krow * HD_ + kcol;
    int klo = krow * 40 + kcol;
    int vd = tid >> 4, g = tid & 15;
    int mbase = 32 * (g >> 3) + 16 * (g & 1) + 4 * ((g >> 1) & 3);
    const short* vgp = V + (size_t)vd * N_ + mbase;
    int vlo = vd * 72 + g * 4;

    short4v kst = *(const short4v*)kgp;
    short4v vst = *(const short4v*)vgp;

    f32x4 s0[4], s1[4];
    short8 vf[4];

    for (int t = 0; t < 64; ++t) {
        int buf = t & 1;
        *(short4v*)&kl[buf * 2560 + klo] = kst;
        *(short4v*)&vl[buf * 2304 + vlo] = vst;
        if (t < 63) {
            kst = *(const short4v*)(kgp + (size_t)(t + 1) * 64 * HD_);
            vst = *(const short4v*)(vgp + (t + 1) * 64);
        }
        __syncthreads();

        __builtin_amdgcn_s_setprio(1);
#pragma unroll
        for (int c = 0; c < 4; c++) {
            short8 kf = *(short8*)&kl[buf * 2560 + (c * 16 + li) * 40 + quad * 8];
            s0[c] = __builtin_amdgcn_mfma_f32_16x16x32_bf16(kf, qf0, zero, 0, 0, 0);
            s1[c] = __builtin_amdgcn_mfma_f32_16x16x32_bf16(kf, qf1, zero, 0, 0, 0);
        }
        __builtin_amdgcn_s_setprio(0);

        vf[0] = *(short8*)&vl[buf * 2304 + li * 72 + quad * 8];
        vf[1] = *(short8*)&vl[buf * 2304 + (16 + li) * 72 + quad * 8];
        vf[2] = *(short8*)&vl[buf * 2304 + li * 72 + 32 + quad * 8];
        vf[3] = *(short8*)&vl[buf * 2304 + (16 + li) * 72 + 32 + quad * 8];

        unsigned paw[8];
        float lp = 0.f;
#pragma unroll
        for (int c = 0; c < 4; c++) {
            float e0 = __builtin_amdgcn_exp2f(s0[c][0]);
            float e1 = __builtin_amdgcn_exp2f(s0[c][1]);
            float e2 = __builtin_amdgcn_exp2f(s0[c][2]);
            float e3 = __builtin_amdgcn_exp2f(s0[c][3]);
            lp += (e0 + e1) + (e2 + e3);
            paw[2 * c]     = __builtin_amdgcn_perm(__float_as_uint(e1), __float_as_uint(e0), 0x07060302);
            paw[2 * c + 1] = __builtin_amdgcn_perm(__float_as_uint(e3), __float_as_uint(e2), 0x07060302);
        }
        lr0 += lp;
        uint4v p0 = (uint4v){paw[0], paw[1], paw[2], paw[3]};
        uint4v p1 = (uint4v){paw[4], paw[5], paw[6], paw[7]};
        short8 a0 = __builtin_bit_cast(short8, p0);
        short8 a1 = __builtin_bit_cast(short8, p1);

        lp = 0.f;
#pragma unroll
        for (int c = 0; c < 4; c++) {
            float e0 = __builtin_amdgcn_exp2f(s1[c][0]);
            float e1 = __builtin_amdgcn_exp2f(s1[c][1]);
            float e2 = __builtin_amdgcn_exp2f(s1[c][2]);
            float e3 = __builtin_amdgcn_exp2f(s1[c][3]);
            lp += (e0 + e1) + (e2 + e3);
            paw[2 * c]     = __builtin_amdgcn_perm(__float_as_uint(e1), __float_as_uint(e0), 0x07060302);
            paw[2 * c + 1] = __builtin_amdgcn_perm(__float_as_uint(e3), __float_as_uint(e2), 0x07060302);
        }
        lr1 += lp;
        uint4v p2 = (uint4v){paw[0], paw[1], paw[2], paw[3]};
        uint4v p3 = (uint4v){paw[4], paw[5], paw[6], paw[7]};
        short8 a2 = __builtin_bit_cast(short8, p2);
        short8 a3 = __builtin_bit_cast(short8, p3);

        __builtin_amdgcn_s_setprio(1);
        oa00 = __builtin_amdgcn_mfma_f32_16x16x32_bf16(a0, vf[0], oa00, 0, 0, 0);
        oa01 = __builtin_amdgcn_mfma_f32_16x16x32_bf16(a0, vf[1], oa01, 0, 0, 0);
        oa00 = __builtin_amdgcn_mfma_f32_16x16x32_bf16(a1, vf[2], oa00, 0, 0, 0);
        oa01 = __builtin_amdgcn_mfma_f32_16x16x32_bf16(a1, vf[3], oa01, 0, 0, 0);
        oa10 = __builtin_amdgcn_mfma_f32_16x16x32_bf16(a2, vf[0], oa10, 0, 0, 0);
        oa11 = __builtin_amdgcn_mfma_f32_16x16x32_bf16(a2, vf[1], oa11, 0, 0, 0);
        oa10 = __builtin_amdgcn_mfma_f32_16x16x32_bf16(a3, vf[2], oa10, 0, 0, 0);
        oa11 = __builtin_amdgcn_mfma_f32_16x16x32_bf16(a3, vf[3], oa11, 0, 0, 0);
        __builtin_amdgcn_s_setprio(0);
    }

    lr0 += __shfl_xor(lr0, 16); lr0 += __shfl_xor(lr0, 32);
    lr1 += __shfl_xor(lr1, 16); lr1 += __shfl_xor(lr1, 32);
#pragma unroll
    for (int r = 0; r < 4; r++) {
        float ln0 = __shfl(lr0, quad * 4 + r);
        float inv0 = 1.f / ln0;
        size_t n_ = (size_t)(n0w + quad * 4 + r);
        O[n_ * 256 + li]      = f2b(oa00[r] * inv0);
        O[n_ * 256 + 16 + li] = f2b(oa01[r] * inv0);
        float ln1 = __shfl(lr1, quad * 4 + r);
        float inv1 = 1.f / ln1;
        size_t n2 = (size_t)(n0w + 16 + quad * 4 + r);
        O[n2 * 256 + li]      = f2b(oa10[r] * inv1);
        O[n2 * 256 + 16 + li] = f2b(oa11[r] * inv1);
    }
}

// ---------------- Node 4: out projection (64x64 tiles, 512 blocks, 2/CU, bf16 W) ----------------
__global__ __launch_bounds__(256) void gemm_out(const short* __restrict__ wob,
                                                const float* __restrict__ bias,
                                                const short* __restrict__ aoT,
                                                const float* __restrict__ resid,
                                                float* __restrict__ out) {
    int b = blockIdx.z;
    const short* X = aoT + (size_t)b * N_ * C_;
    const float* R = resid + (size_t)b * C_ * N_;
    float* outp = out + (size_t)b * C_ * N_;

    __shared__ short wl[64][40];
    __shared__ short xl[64][40];

    int o0 = blockIdx.y * 64, n0 = blockIdx.x * 64;
    int tid = threadIdx.x;
    int w = tid >> 6, lane = tid & 63, li = lane & 15, quad = lane >> 4;
    int wr = w & 1, wc = w >> 1;

    f32x4 acc[2][2];
#pragma unroll
    for (int i = 0; i < 2; i++)
#pragma unroll
        for (int j = 0; j < 2; j++) acc[i][j] = (f32x4){0.f, 0.f, 0.f, 0.f};

    int row = tid >> 2, co = (tid & 3) << 3;
    for (int k0 = 0; k0 < 256; k0 += 32) {
        *(short8*)&wl[row][co] = *(const short8*)&wob[(size_t)(o0 + row) * 256 + k0 + co];
        *(short8*)&xl[row][co] = *(const short8*)&X[(size_t)(n0 + row) * 256 + k0 + co];
        __syncthreads();
        short8 af[2], bfr[2];
#pragma unroll
        for (int i = 0; i < 2; i++) af[i]  = *(short8*)&wl[wr * 32 + i * 16 + li][quad * 8];
#pragma unroll
        for (int j = 0; j < 2; j++) bfr[j] = *(short8*)&xl[wc * 32 + j * 16 + li][quad * 8];
#pragma unroll
        for (int i = 0; i < 2; i++)
#pragma unroll
            for (int j = 0; j < 2; j++)
                acc[i][j] = __builtin_amdgcn_mfma_f32_16x16x32_bf16(af[i], bfr[j], acc[i][j], 0, 0, 0);
        __syncthreads();
    }
#pragma unroll
    for (int i = 0; i < 2; i++) {
        int ob = o0 + wr * 32 + i * 16 + quad * 4;
#pragma unroll
        for (int j = 0; j < 2; j++) {
            int n_ = n0 + wc * 32 + j * 16 + li;
#pragma unroll
            for (int r = 0; r < 4; r++) {
                size_t idx = (size_t)(ob + r) * N_ + n_;
                outp[idx] = acc[i][j][r] + bias[ob + r] + R[idx];
            }
        }
    }
}

extern "C" void kernel_launch(void* const* d_in, const int* in_sizes, int n_in,
                              void* d_out, int out_size, void* d_ws, size_t ws_size,
                              hipStream_t stream) {
    const float* x  = (const float*)d_in[0];
    const float* gw = (const float*)d_in[1];
    const float* gb = (const float*)d_in[2];
    const float* wq = (const float*)d_in[3];
    const float* bq = (const float*)d_in[4];
    const float* wk = (const float*)d_in[5];
    const float* bk = (const float*)d_in[6];
    const float* wv = (const float*)d_in[7];
    const float* bv = (const float*)d_in[8];
    const float* wo = (const float*)d_in[9];
    const float* bo = (const float*)d_in[10];
    float* out = (float*)d_out;

    char* ws = (char*)d_ws;
    float* part = (float*)ws;                  // 2048 floats
    const size_t TS = (size_t)B_ * N_ * C_;
    short* aoT = (short*)(ws + 16384);         // flash output [b][n][c] bf16 (normalized)
    short* q   = aoT + TS;
    short* kt  = q + TS;                       // packed [b*8+h][m][32]
    short* v   = kt + TS;
    short* wb  = v + TS;                       // bf16 weights [wq|wk|wv|wo], 4*65536 shorts

    prep<<<1152, 256, 0, stream>>>(x, part, wq, wk, wv, wo, wb);
    gemm_qkv<<<dim3(128, 2), 512, 0, stream>>>(x, gw, gb, part, wb,
                                               bq, bk, bv, q, kt, v);
    flash<<<256, 512, 0, stream>>>(q, kt, v, aoT);
    gemm_out<<<dim3(64, 4, 2), 256, 0, stream>>>(wb + 3 * 65536, bo, aoT, x, out);
}

// Round 10
// 147.226 us; speedup vs baseline: 1.0355x; 1.0355x over previous
//
#include <hip/hip_runtime.h>

#define B_   2
#define C_   256
#define N_   4096
#define H_   8
#define HD_  32
#define G_   8
#define CPG_ 32

typedef short short8 __attribute__((ext_vector_type(8)));
typedef short short4v __attribute__((ext_vector_type(4)));
typedef unsigned uint4v __attribute__((ext_vector_type(4)));
typedef float f32x4  __attribute__((ext_vector_type(4)));
typedef float f4     __attribute__((ext_vector_type(4)));

__device__ __forceinline__ float b2f(short s) {
    return __uint_as_float(((unsigned)(unsigned short)s) << 16);
}
__device__ __forceinline__ short f2b(float f) {
    unsigned u = __float_as_uint(f);
    unsigned r = (u + 0x7FFF + ((u >> 16) & 1)) >> 16;  // RNE
    return (short)r;
}

// ---------------- Node 1: GN partial sums + W bf16 conversion (1152 blocks) ----------------
__global__ __launch_bounds__(256) void prep(const float* __restrict__ x,
                                            float* __restrict__ part,
                                            const float* __restrict__ wq,
                                            const float* __restrict__ wk,
                                            const float* __restrict__ wv,
                                            const float* __restrict__ wo,
                                            short* __restrict__ wb) {
    int blk = blockIdx.x;
    if (blk < 1024) {
        const f4* p = (const f4*)x + (size_t)(blk >> 6) * (CPG_ * N_ / 4) + (size_t)(blk & 63) * 512;
        float s = 0.f, ss = 0.f;
#pragma unroll
        for (int i = 0; i < 2; i++) {
            f4 v = p[threadIdx.x + i * 256];
#pragma unroll
            for (int j = 0; j < 4; j++) { float f = v[j]; s += f; ss += f * f; }
        }
#pragma unroll
        for (int off = 32; off > 0; off >>= 1) {
            s  += __shfl_down(s, off);
            ss += __shfl_down(ss, off);
        }
        __shared__ float rs[4], rss[4];
        int w = threadIdx.x >> 6;
        if ((threadIdx.x & 63) == 0) { rs[w] = s; rss[w] = ss; }
        __syncthreads();
        if (threadIdx.x == 0) {
            part[blk * 2]     = rs[0] + rs[1] + rs[2] + rs[3];
            part[blk * 2 + 1] = rss[0] + rss[1] + rss[2] + rss[3];
        }
    } else {
        int gid = (blk - 1024) * 256 + threadIdx.x;    // 0..32767
        int rid = gid >> 13;                           // 0..3
        int off = (gid & 8191) * 8;
        const float* src = rid == 0 ? wq : (rid == 1 ? wk : (rid == 2 ? wv : wo));
        f4 a = *(const f4*)(src + off);
        f4 b = *(const f4*)(src + off + 4);
        short8 r;
#pragma unroll
        for (int j = 0; j < 4; j++) { r[j] = f2b(a[j]); r[j + 4] = f2b(b[j]); }
        *(short8*)&wb[(size_t)rid * 65536 + off] = r;
    }
}

// ---------------- Node 2: merged GN-apply + QKV GEMM (512 blocks, 2/CU) — R8 proven ----------------
__global__ __launch_bounds__(256, 2) void gemm_qkv(
    const float* __restrict__ x,
    const float* __restrict__ gw, const float* __restrict__ gb,
    const float* __restrict__ part,
    const short* __restrict__ wb,
    const float* __restrict__ bq, const float* __restrict__ bk,
    const float* __restrict__ bv,
    short* __restrict__ q, short* __restrict__ kt, short* __restrict__ v) {
    int b = blockIdx.z;
    int o0 = blockIdx.y * 64, n0 = blockIdx.x * 64;
    const float mul = 0.17677669529663687f * 1.4426950408889634f;

    __shared__ short wl[3][64][40];
    __shared__ short xl[64][40];
    __shared__ float ga[256], gbb[256];
    __shared__ float mus[8], rstds[8];

    int tid = threadIdx.x;
    int w = tid >> 6, lane = tid & 63, li = lane & 15, quad = lane >> 4;
    int wr = w & 1, wc = w >> 1;

#pragma unroll
    for (int gi = 0; gi < 2; gi++) {
        int g = w * 2 + gi;
        const float* pp = &part[(size_t)(b * 8 + g) * 128 + lane * 2];
        float s = pp[0], ss = pp[1];
#pragma unroll
        for (int off = 32; off > 0; off >>= 1) {
            s  += __shfl_down(s, off);
            ss += __shfl_down(ss, off);
        }
        if (lane == 0) {
            const float inv = 1.f / (float)(CPG_ * N_);
            float mu = s * inv;
            float var = ss * inv - mu * mu;
            mus[g] = mu;
            rstds[g] = rsqrtf(var + 1e-5f);
        }
    }
    __syncthreads();
    {
        int c = tid, g = c >> 5;
        float a = rstds[g] * gw[c];
        ga[c]  = a;
        gbb[c] = gb[c] - mus[g] * a;
    }

    f32x4 aq[2][2], ak[2][2], av[2][2];
#pragma unroll
    for (int i = 0; i < 2; i++)
#pragma unroll
        for (int j = 0; j < 2; j++) {
            aq[i][j] = (f32x4){0.f, 0.f, 0.f, 0.f};
            ak[i][j] = (f32x4){0.f, 0.f, 0.f, 0.f};
            av[i][j] = (f32x4){0.f, 0.f, 0.f, 0.f};
        }

    int wrow = tid >> 2, wco = (tid & 3) << 3;
    int cpair = tid >> 4, l16 = tid & 15;
    __syncthreads();

    for (int k0 = 0; k0 < 256; k0 += 32) {
#pragma unroll
        for (int m = 0; m < 3; m++)
            *(short8*)&wl[m][wrow][wco] =
                *(const short8*)&wb[(size_t)m * 65536 + (size_t)(o0 + wrow) * 256 + k0 + wco];
        {
            int c0 = k0 + cpair * 2;
            float a0 = ga[c0],     b0c = gbb[c0];
            float a1 = ga[c0 + 1], b1c = gbb[c0 + 1];
            const float* xr0 = x + ((size_t)(b * 256 + c0)) * N_ + n0 + l16;
            const float* xr1 = xr0 + N_;
#pragma unroll
            for (int j = 0; j < 4; j++) {
                unsigned lo = (unsigned short)f2b(xr0[16 * j] * a0 + b0c);
                unsigned hi = (unsigned short)f2b(xr1[16 * j] * a1 + b1c);
                *(unsigned*)&xl[l16 + 16 * j][cpair * 2] = lo | (hi << 16);
            }
        }
        __syncthreads();

        short8 xf[2];
#pragma unroll
        for (int i = 0; i < 2; i++)
            xf[i] = *(short8*)&xl[wc * 32 + i * 16 + li][quad * 8];
#pragma unroll
        for (int j = 0; j < 2; j++) {
            short8 wfq = *(short8*)&wl[0][wr * 32 + j * 16 + li][quad * 8];
            short8 wfk = *(short8*)&wl[1][wr * 32 + j * 16 + li][quad * 8];
            short8 wfv = *(short8*)&wl[2][wr * 32 + j * 16 + li][quad * 8];
#pragma unroll
            for (int i = 0; i < 2; i++) {
                aq[i][j] = __builtin_amdgcn_mfma_f32_16x16x32_bf16(xf[i], wfq, aq[i][j], 0, 0, 0);
                ak[i][j] = __builtin_amdgcn_mfma_f32_16x16x32_bf16(xf[i], wfk, ak[i][j], 0, 0, 0);
                av[j][i] = __builtin_amdgcn_mfma_f32_16x16x32_bf16(wfv, xf[i], av[j][i], 0, 0, 0);
            }
        }
        __syncthreads();
    }

    {   // Q^T [b][n][c], scaled
        short* outp = q + (size_t)b * N_ * C_;
#pragma unroll
        for (int i = 0; i < 2; i++) {
            int nb_ = n0 + wc * 32 + i * 16 + quad * 4;
#pragma unroll
            for (int j = 0; j < 2; j++) {
                int o_ = o0 + wr * 32 + j * 16 + li;
                float bv_ = bq[o_];
#pragma unroll
                for (int r = 0; r < 4; r++)
                    outp[(size_t)(nb_ + r) * C_ + o_] = f2b((aq[i][j][r] + bv_) * mul);
            }
        }
    }
    {   // K packed [b*8+h][m][32]
#pragma unroll
        for (int i = 0; i < 2; i++) {
            int nb_ = n0 + wc * 32 + i * 16 + quad * 4;
#pragma unroll
            for (int j = 0; j < 2; j++) {
                int o_ = o0 + wr * 32 + j * 16 + li;
                int hh = o_ >> 5, d = o_ & 31;
                float bv_ = bk[o_];
                short* kdst = kt + ((size_t)(b * 8 + hh) * N_) * HD_ + d;
#pragma unroll
                for (int r = 0; r < 4; r++)
                    kdst[(size_t)(nb_ + r) * HD_] = f2b(ak[i][j][r] + bv_);
            }
        }
    }
    {   // V [b][c][n]
        short* outp = v + (size_t)b * C_ * N_;
#pragma unroll
        for (int j = 0; j < 2; j++) {
            int ob = o0 + wr * 32 + j * 16 + quad * 4;
#pragma unroll
            for (int i = 0; i < 2; i++) {
                int n_ = n0 + wc * 32 + i * 16 + li;
#pragma unroll
                for (int r = 0; r < 4; r++)
                    outp[(size_t)(ob + r) * N_ + n_] = f2b(av[j][i][r] + bv[ob + r]);
            }
        }
    }
}

// ---------------- Node 3: flash v19 — KVBLK=128, two independent chunk-chains per barrier ----------------
// 256 blocks x 512 threads (8 waves x 32 Q-rows), 32 tiles of 128 KV = 2 chunks of 64.
// Per barrier: QK(A), QK(B) [MFMA, fills exp(A)'s shadow], exp(A), PV(A), exp(B), PV(B).
// Halves barrier count; within-wave ILP decouples VALU bursts from MFMA bursts.
// Staging/fragment/epilogue code identical to proven v18 (per chunk).
#define EXPPACK(sx, lrx, A0, A1)                                          \
    {                                                                     \
        unsigned paw[8];                                                  \
        float lp = 0.f;                                                   \
        _Pragma("unroll")                                                 \
        for (int c = 0; c < 4; c++) {                                     \
            float e0 = __builtin_amdgcn_exp2f(sx[c][0]);                  \
            float e1 = __builtin_amdgcn_exp2f(sx[c][1]);                  \
            float e2 = __builtin_amdgcn_exp2f(sx[c][2]);                  \
            float e3 = __builtin_amdgcn_exp2f(sx[c][3]);                  \
            lp += (e0 + e1) + (e2 + e3);                                  \
            paw[2 * c]     = __builtin_amdgcn_perm(__float_as_uint(e1), __float_as_uint(e0), 0x07060302); \
            paw[2 * c + 1] = __builtin_amdgcn_perm(__float_as_uint(e3), __float_as_uint(e2), 0x07060302); \
        }                                                                 \
        lrx += lp;                                                        \
        uint4v p0_ = (uint4v){paw[0], paw[1], paw[2], paw[3]};            \
        uint4v p1_ = (uint4v){paw[4], paw[5], paw[6], paw[7]};            \
        A0 = __builtin_bit_cast(short8, p0_);                             \
        A1 = __builtin_bit_cast(short8, p1_);                             \
    }

__global__ __launch_bounds__(512, 2) void flash(const short* __restrict__ q,
                                                const short* __restrict__ ktp,
                                                const short* __restrict__ v,
                                                short* __restrict__ aoT) {
    int bid = blockIdx.x;          // 0..255
    int xcd = bid & 7;
    int rest = bid >> 3;           // 0..31
    int bh = xcd * 2 + (rest & 1);
    int nb = rest >> 1;            // 0..15 -> 256 rows each
    int b = bh >> 3, h = bh & 7;

    const short* QT = q   + (size_t)b * N_ * C_ + h * HD_;
    const short* KP = ktp + (size_t)bh * N_ * HD_;
    const short* V  = v   + ((size_t)b * C_ + h * HD_) * N_;
    short* O = aoT + (size_t)b * N_ * C_ + h * HD_;

    __shared__ short kl[2 * 5120];   // 2 chunks x (64 m-rows x 32 d, stride 40)
    __shared__ short vl[2 * 4608];   // 2 chunks x (32 d-rows x 64 slots, stride 72)

    int tid = threadIdx.x, w = tid >> 6, lane = tid & 63, li = lane & 15, quad = lane >> 4;
    int n0w = nb * 256 + w * 32;     // 8 waves x 32 rows

    short8 qf0 = *(const short8*)&QT[(size_t)(n0w + li) * 256 + quad * 8];
    short8 qf1 = *(const short8*)&QT[(size_t)(n0w + 16 + li) * 256 + quad * 8];

    f32x4 oa00 = (f32x4){0.f,0.f,0.f,0.f}, oa01 = oa00, oa10 = oa00, oa11 = oa00;
    float lr0 = 0.f, lr1 = 0.f;
    const f32x4 zero = (f32x4){0.f, 0.f, 0.f, 0.f};

    int krow = tid >> 3, kcol = (tid & 7) << 2;
    const short* kgp = KP + (size_t)krow * HD_ + kcol;
    int klo = krow * 40 + kcol;
    int vd = tid >> 4, g = tid & 15;
    int mbase = 32 * (g >> 3) + 16 * (g & 1) + 4 * ((g >> 1) & 3);
    const short* vgp = V + (size_t)vd * N_ + mbase;
    int vlo = vd * 72 + g * 4;

    short4v kstA = *(const short4v*)kgp;
    short4v kstB = *(const short4v*)(kgp + (size_t)64 * HD_);
    short4v vstA = *(const short4v*)vgp;
    short4v vstB = *(const short4v*)(vgp + 64);

    f32x4 s0a[4], s1a[4], s0b[4], s1b[4];
    short8 vf[4];

    for (int t = 0; t < 32; ++t) {
        int buf = t & 1;
        *(short4v*)&kl[buf * 5120 + klo] = kstA;
        *(short4v*)&kl[buf * 5120 + 2560 + klo] = kstB;
        *(short4v*)&vl[buf * 4608 + vlo] = vstA;
        *(short4v*)&vl[buf * 4608 + 2304 + vlo] = vstB;
        if (t < 31) {
            const short* kq = kgp + (size_t)(t + 1) * 128 * HD_;
            kstA = *(const short4v*)kq;
            kstB = *(const short4v*)(kq + (size_t)64 * HD_);
            const short* vq = vgp + (t + 1) * 128;
            vstA = *(const short4v*)vq;
            vstB = *(const short4v*)(vq + 64);
        }
        __syncthreads();

        // QK chunk A then chunk B (B's MFMAs fill exp(A)'s dependency shadow)
        __builtin_amdgcn_s_setprio(1);
#pragma unroll
        for (int c = 0; c < 4; c++) {
            short8 kf = *(short8*)&kl[buf * 5120 + (c * 16 + li) * 40 + quad * 8];
            s0a[c] = __builtin_amdgcn_mfma_f32_16x16x32_bf16(kf, qf0, zero, 0, 0, 0);
            s1a[c] = __builtin_amdgcn_mfma_f32_16x16x32_bf16(kf, qf1, zero, 0, 0, 0);
        }
#pragma unroll
        for (int c = 0; c < 4; c++) {
            short8 kf = *(short8*)&kl[buf * 5120 + 2560 + (c * 16 + li) * 40 + quad * 8];
            s0b[c] = __builtin_amdgcn_mfma_f32_16x16x32_bf16(kf, qf0, zero, 0, 0, 0);
            s1b[c] = __builtin_amdgcn_mfma_f32_16x16x32_bf16(kf, qf1, zero, 0, 0, 0);
        }
        __builtin_amdgcn_s_setprio(0);

        // ---- chunk A ----
        vf[0] = *(short8*)&vl[buf * 4608 + li * 72 + quad * 8];
        vf[1] = *(short8*)&vl[buf * 4608 + (16 + li) * 72 + quad * 8];
        vf[2] = *(short8*)&vl[buf * 4608 + li * 72 + 32 + quad * 8];
        vf[3] = *(short8*)&vl[buf * 4608 + (16 + li) * 72 + 32 + quad * 8];

        short8 a0, a1, a2, a3;
        EXPPACK(s0a, lr0, a0, a1);
        EXPPACK(s1a, lr1, a2, a3);

        __builtin_amdgcn_s_setprio(1);
        oa00 = __builtin_amdgcn_mfma_f32_16x16x32_bf16(a0, vf[0], oa00, 0, 0, 0);
        oa01 = __builtin_amdgcn_mfma_f32_16x16x32_bf16(a0, vf[1], oa01, 0, 0, 0);
        oa00 = __builtin_amdgcn_mfma_f32_16x16x32_bf16(a1, vf[2], oa00, 0, 0, 0);
        oa01 = __builtin_amdgcn_mfma_f32_16x16x32_bf16(a1, vf[3], oa01, 0, 0, 0);
        oa10 = __builtin_amdgcn_mfma_f32_16x16x32_bf16(a2, vf[0], oa10, 0, 0, 0);
        oa11 = __builtin_amdgcn_mfma_f32_16x16x32_bf16(a2, vf[1], oa11, 0, 0, 0);
        oa10 = __builtin_amdgcn_mfma_f32_16x16x32_bf16(a3, vf[2], oa10, 0, 0, 0);
        oa11 = __builtin_amdgcn_mfma_f32_16x16x32_bf16(a3, vf[3], oa11, 0, 0, 0);
        __builtin_amdgcn_s_setprio(0);

        // ---- chunk B ----
        vf[0] = *(short8*)&vl[buf * 4608 + 2304 + li * 72 + quad * 8];
        vf[1] = *(short8*)&vl[buf * 4608 + 2304 + (16 + li) * 72 + quad * 8];
        vf[2] = *(short8*)&vl[buf * 4608 + 2304 + li * 72 + 32 + quad * 8];
        vf[3] = *(short8*)&vl[buf * 4608 + 2304 + (16 + li) * 72 + 32 + quad * 8];

        EXPPACK(s0b, lr0, a0, a1);
        EXPPACK(s1b, lr1, a2, a3);

        __builtin_amdgcn_s_setprio(1);
        oa00 = __builtin_amdgcn_mfma_f32_16x16x32_bf16(a0, vf[0], oa00, 0, 0, 0);
        oa01 = __builtin_amdgcn_mfma_f32_16x16x32_bf16(a0, vf[1], oa01, 0, 0, 0);
        oa00 = __builtin_amdgcn_mfma_f32_16x16x32_bf16(a1, vf[2], oa00, 0, 0, 0);
        oa01 = __builtin_amdgcn_mfma_f32_16x16x32_bf16(a1, vf[3], oa01, 0, 0, 0);
        oa10 = __builtin_amdgcn_mfma_f32_16x16x32_bf16(a2, vf[0], oa10, 0, 0, 0);
        oa11 = __builtin_amdgcn_mfma_f32_16x16x32_bf16(a2, vf[1], oa11, 0, 0, 0);
        oa10 = __builtin_amdgcn_mfma_f32_16x16x32_bf16(a3, vf[2], oa10, 0, 0, 0);
        oa11 = __builtin_amdgcn_mfma_f32_16x16x32_bf16(a3, vf[3], oa11, 0, 0, 0);
        __builtin_amdgcn_s_setprio(0);
    }

    lr0 += __shfl_xor(lr0, 16); lr0 += __shfl_xor(lr0, 32);
    lr1 += __shfl_xor(lr1, 16); lr1 += __shfl_xor(lr1, 32);
#pragma unroll
    for (int r = 0; r < 4; r++) {
        float ln0 = __shfl(lr0, quad * 4 + r);
        float inv0 = 1.f / ln0;
        size_t n_ = (size_t)(n0w + quad * 4 + r);
        O[n_ * 256 + li]      = f2b(oa00[r] * inv0);
        O[n_ * 256 + 16 + li] = f2b(oa01[r] * inv0);
        float ln1 = __shfl(lr1, quad * 4 + r);
        float inv1 = 1.f / ln1;
        size_t n2 = (size_t)(n0w + 16 + quad * 4 + r);
        O[n2 * 256 + li]      = f2b(oa10[r] * inv1);
        O[n2 * 256 + 16 + li] = f2b(oa11[r] * inv1);
    }
}

// ---------------- Node 4: out projection (64x64 tiles, 512 blocks, 2/CU, bf16 W) ----------------
__global__ __launch_bounds__(256) void gemm_out(const short* __restrict__ wob,
                                                const float* __restrict__ bias,
                                                const short* __restrict__ aoT,
                                                const float* __restrict__ resid,
                                                float* __restrict__ out) {
    int b = blockIdx.z;
    const short* X = aoT + (size_t)b * N_ * C_;
    const float* R = resid + (size_t)b * C_ * N_;
    float* outp = out + (size_t)b * C_ * N_;

    __shared__ short wl[64][40];
    __shared__ short xl[64][40];

    int o0 = blockIdx.y * 64, n0 = blockIdx.x * 64;
    int tid = threadIdx.x;
    int w = tid >> 6, lane = tid & 63, li = lane & 15, quad = lane >> 4;
    int wr = w & 1, wc = w >> 1;

    f32x4 acc[2][2];
#pragma unroll
    for (int i = 0; i < 2; i++)
#pragma unroll
        for (int j = 0; j < 2; j++) acc[i][j] = (f32x4){0.f, 0.f, 0.f, 0.f};

    int row = tid >> 2, co = (tid & 3) << 3;
    for (int k0 = 0; k0 < 256; k0 += 32) {
        *(short8*)&wl[row][co] = *(const short8*)&wob[(size_t)(o0 + row) * 256 + k0 + co];
        *(short8*)&xl[row][co] = *(const short8*)&X[(size_t)(n0 + row) * 256 + k0 + co];
        __syncthreads();
        short8 af[2], bfr[2];
#pragma unroll
        for (int i = 0; i < 2; i++) af[i]  = *(short8*)&wl[wr * 32 + i * 16 + li][quad * 8];
#pragma unroll
        for (int j = 0; j < 2; j++) bfr[j] = *(short8*)&xl[wc * 32 + j * 16 + li][quad * 8];
#pragma unroll
        for (int i = 0; i < 2; i++)
#pragma unroll
            for (int j = 0; j < 2; j++)
                acc[i][j] = __builtin_amdgcn_mfma_f32_16x16x32_bf16(af[i], bfr[j], acc[i][j], 0, 0, 0);
        __syncthreads();
    }
#pragma unroll
    for (int i = 0; i < 2; i++) {
        int ob = o0 + wr * 32 + i * 16 + quad * 4;
#pragma unroll
        for (int j = 0; j < 2; j++) {
            int n_ = n0 + wc * 32 + j * 16 + li;
#pragma unroll
            for (int r = 0; r < 4; r++) {
                size_t idx = (size_t)(ob + r) * N_ + n_;
                outp[idx] = acc[i][j][r] + bias[ob + r] + R[idx];
            }
        }
    }
}

extern "C" void kernel_launch(void* const* d_in, const int* in_sizes, int n_in,
                              void* d_out, int out_size, void* d_ws, size_t ws_size,
                              hipStream_t stream) {
    const float* x  = (const float*)d_in[0];
    const float* gw = (const float*)d_in[1];
    const float* gb = (const float*)d_in[2];
    const float* wq = (const float*)d_in[3];
    const float* bq = (const float*)d_in[4];
    const float* wk = (const float*)d_in[5];
    const float* bk = (const float*)d_in[6];
    const float* wv = (const float*)d_in[7];
    const float* bv = (const float*)d_in[8];
    const float* wo = (const float*)d_in[9];
    const float* bo = (const float*)d_in[10];
    float* out = (float*)d_out;

    char* ws = (char*)d_ws;
    float* part = (float*)ws;                  // 2048 floats
    const size_t TS = (size_t)B_ * N_ * C_;
    short* aoT = (short*)(ws + 16384);         // flash output [b][n][c] bf16 (normalized)
    short* q   = aoT + TS;
    short* kt  = q + TS;                       // packed [b*8+h][m][32]
    short* v   = kt + TS;
    short* wb  = v + TS;                       // bf16 weights [wq|wk|wv|wo], 4*65536 shorts

    prep<<<1152, 256, 0, stream>>>(x, part, wq, wk, wv, wo, wb);
    gemm_qkv<<<dim3(64, 4, 2), 256, 0, stream>>>(x, gw, gb, part, wb,
                                                 bq, bk, bv, q, kt, v);
    flash<<<256, 512, 0, stream>>>(q, kt, v, aoT);
    gemm_out<<<dim3(64, 4, 2), 256, 0, stream>>>(wb + 3 * 65536, bo, aoT, x, out);
}

// Round 11
// 145.220 us; speedup vs baseline: 1.0498x; 1.0138x over previous
//
#include <hip/hip_runtime.h>

#define B_   2
#define C_   256
#define N_   4096
#define H_   8
#define HD_  32
#define G_   8
#define CPG_ 32

typedef short short8 __attribute__((ext_vector_type(8)));
typedef short short4v __attribute__((ext_vector_type(4)));
typedef unsigned uint4v __attribute__((ext_vector_type(4)));
typedef float f32x4  __attribute__((ext_vector_type(4)));
typedef float f4     __attribute__((ext_vector_type(4)));

__device__ __forceinline__ float b2f(short s) {
    return __uint_as_float(((unsigned)(unsigned short)s) << 16);
}
__device__ __forceinline__ short f2b(float f) {
    unsigned u = __float_as_uint(f);
    unsigned r = (u + 0x7FFF + ((u >> 16) & 1)) >> 16;  // RNE
    return (short)r;
}

// ---------------- Node 1: GN partial sums + W bf16 conversion (1152 blocks) ----------------
__global__ __launch_bounds__(256) void prep(const float* __restrict__ x,
                                            float* __restrict__ part,
                                            const float* __restrict__ wq,
                                            const float* __restrict__ wk,
                                            const float* __restrict__ wv,
                                            const float* __restrict__ wo,
                                            short* __restrict__ wb) {
    int blk = blockIdx.x;
    if (blk < 1024) {
        const f4* p = (const f4*)x + (size_t)(blk >> 6) * (CPG_ * N_ / 4) + (size_t)(blk & 63) * 512;
        float s = 0.f, ss = 0.f;
#pragma unroll
        for (int i = 0; i < 2; i++) {
            f4 v = p[threadIdx.x + i * 256];
#pragma unroll
            for (int j = 0; j < 4; j++) { float f = v[j]; s += f; ss += f * f; }
        }
#pragma unroll
        for (int off = 32; off > 0; off >>= 1) {
            s  += __shfl_down(s, off);
            ss += __shfl_down(ss, off);
        }
        __shared__ float rs[4], rss[4];
        int w = threadIdx.x >> 6;
        if ((threadIdx.x & 63) == 0) { rs[w] = s; rss[w] = ss; }
        __syncthreads();
        if (threadIdx.x == 0) {
            part[blk * 2]     = rs[0] + rs[1] + rs[2] + rs[3];
            part[blk * 2 + 1] = rss[0] + rss[1] + rss[2] + rss[3];
        }
    } else {
        int gid = (blk - 1024) * 256 + threadIdx.x;    // 0..32767
        int rid = gid >> 13;                           // 0..3
        int off = (gid & 8191) * 8;
        const float* src = rid == 0 ? wq : (rid == 1 ? wk : (rid == 2 ? wv : wo));
        f4 a = *(const f4*)(src + off);
        f4 b = *(const f4*)(src + off + 4);
        short8 r;
#pragma unroll
        for (int j = 0; j < 4; j++) { r[j] = f2b(a[j]); r[j + 4] = f2b(b[j]); }
        *(short8*)&wb[(size_t)rid * 65536 + off] = r;
    }
}

// ---------------- Node 2: merged GN-apply + QKV GEMM (512 blocks, 2/CU) — R8 proven ----------------
__global__ __launch_bounds__(256, 2) void gemm_qkv(
    const float* __restrict__ x,
    const float* __restrict__ gw, const float* __restrict__ gb,
    const float* __restrict__ part,
    const short* __restrict__ wb,
    const float* __restrict__ bq, const float* __restrict__ bk,
    const float* __restrict__ bv,
    short* __restrict__ q, short* __restrict__ kt, short* __restrict__ v) {
    int b = blockIdx.z;
    int o0 = blockIdx.y * 64, n0 = blockIdx.x * 64;
    const float mul = 0.17677669529663687f * 1.4426950408889634f;

    __shared__ short wl[3][64][40];
    __shared__ short xl[64][40];
    __shared__ float ga[256], gbb[256];
    __shared__ float mus[8], rstds[8];

    int tid = threadIdx.x;
    int w = tid >> 6, lane = tid & 63, li = lane & 15, quad = lane >> 4;
    int wr = w & 1, wc = w >> 1;

#pragma unroll
    for (int gi = 0; gi < 2; gi++) {
        int g = w * 2 + gi;
        const float* pp = &part[(size_t)(b * 8 + g) * 128 + lane * 2];
        float s = pp[0], ss = pp[1];
#pragma unroll
        for (int off = 32; off > 0; off >>= 1) {
            s  += __shfl_down(s, off);
            ss += __shfl_down(ss, off);
        }
        if (lane == 0) {
            const float inv = 1.f / (float)(CPG_ * N_);
            float mu = s * inv;
            float var = ss * inv - mu * mu;
            mus[g] = mu;
            rstds[g] = rsqrtf(var + 1e-5f);
        }
    }
    __syncthreads();
    {
        int c = tid, g = c >> 5;
        float a = rstds[g] * gw[c];
        ga[c]  = a;
        gbb[c] = gb[c] - mus[g] * a;
    }

    f32x4 aq[2][2], ak[2][2], av[2][2];
#pragma unroll
    for (int i = 0; i < 2; i++)
#pragma unroll
        for (int j = 0; j < 2; j++) {
            aq[i][j] = (f32x4){0.f, 0.f, 0.f, 0.f};
            ak[i][j] = (f32x4){0.f, 0.f, 0.f, 0.f};
            av[i][j] = (f32x4){0.f, 0.f, 0.f, 0.f};
        }

    int wrow = tid >> 2, wco = (tid & 3) << 3;
    int cpair = tid >> 4, l16 = tid & 15;
    __syncthreads();

    for (int k0 = 0; k0 < 256; k0 += 32) {
#pragma unroll
        for (int m = 0; m < 3; m++)
            *(short8*)&wl[m][wrow][wco] =
                *(const short8*)&wb[(size_t)m * 65536 + (size_t)(o0 + wrow) * 256 + k0 + wco];
        {
            int c0 = k0 + cpair * 2;
            float a0 = ga[c0],     b0c = gbb[c0];
            float a1 = ga[c0 + 1], b1c = gbb[c0 + 1];
            const float* xr0 = x + ((size_t)(b * 256 + c0)) * N_ + n0 + l16;
            const float* xr1 = xr0 + N_;
#pragma unroll
            for (int j = 0; j < 4; j++) {
                unsigned lo = (unsigned short)f2b(xr0[16 * j] * a0 + b0c);
                unsigned hi = (unsigned short)f2b(xr1[16 * j] * a1 + b1c);
                *(unsigned*)&xl[l16 + 16 * j][cpair * 2] = lo | (hi << 16);
            }
        }
        __syncthreads();

        short8 xf[2];
#pragma unroll
        for (int i = 0; i < 2; i++)
            xf[i] = *(short8*)&xl[wc * 32 + i * 16 + li][quad * 8];
#pragma unroll
        for (int j = 0; j < 2; j++) {
            short8 wfq = *(short8*)&wl[0][wr * 32 + j * 16 + li][quad * 8];
            short8 wfk = *(short8*)&wl[1][wr * 32 + j * 16 + li][quad * 8];
            short8 wfv = *(short8*)&wl[2][wr * 32 + j * 16 + li][quad * 8];
#pragma unroll
            for (int i = 0; i < 2; i++) {
                aq[i][j] = __builtin_amdgcn_mfma_f32_16x16x32_bf16(xf[i], wfq, aq[i][j], 0, 0, 0);
                ak[i][j] = __builtin_amdgcn_mfma_f32_16x16x32_bf16(xf[i], wfk, ak[i][j], 0, 0, 0);
                av[j][i] = __builtin_amdgcn_mfma_f32_16x16x32_bf16(wfv, xf[i], av[j][i], 0, 0, 0);
            }
        }
        __syncthreads();
    }

    {   // Q^T [b][n][c], scaled
        short* outp = q + (size_t)b * N_ * C_;
#pragma unroll
        for (int i = 0; i < 2; i++) {
            int nb_ = n0 + wc * 32 + i * 16 + quad * 4;
#pragma unroll
            for (int j = 0; j < 2; j++) {
                int o_ = o0 + wr * 32 + j * 16 + li;
                float bv_ = bq[o_];
#pragma unroll
                for (int r = 0; r < 4; r++)
                    outp[(size_t)(nb_ + r) * C_ + o_] = f2b((aq[i][j][r] + bv_) * mul);
            }
        }
    }
    {   // K packed [b*8+h][m][32]
#pragma unroll
        for (int i = 0; i < 2; i++) {
            int nb_ = n0 + wc * 32 + i * 16 + quad * 4;
#pragma unroll
            for (int j = 0; j < 2; j++) {
                int o_ = o0 + wr * 32 + j * 16 + li;
                int hh = o_ >> 5, d = o_ & 31;
                float bv_ = bk[o_];
                short* kdst = kt + ((size_t)(b * 8 + hh) * N_) * HD_ + d;
#pragma unroll
                for (int r = 0; r < 4; r++)
                    kdst[(size_t)(nb_ + r) * HD_] = f2b(ak[i][j][r] + bv_);
            }
        }
    }
    {   // V [b][c][n]
        short* outp = v + (size_t)b * C_ * N_;
#pragma unroll
        for (int j = 0; j < 2; j++) {
            int ob = o0 + wr * 32 + j * 16 + quad * 4;
#pragma unroll
            for (int i = 0; i < 2; i++) {
                int n_ = n0 + wc * 32 + i * 16 + li;
#pragma unroll
                for (int r = 0; r < 4; r++)
                    outp[(size_t)(ob + r) * N_ + n_] = f2b(av[j][i][r] + bv[ob + r]);
            }
        }
    }
}

// ---------------- Node 3: flash v18 — proven 54.0 us (R8), SP=1, fused normalize ----------------
__global__ __launch_bounds__(512) void flash(const short* __restrict__ q,
                                             const short* __restrict__ ktp,
                                             const short* __restrict__ v,
                                             short* __restrict__ aoT) {
    int bid = blockIdx.x;          // 0..255
    int xcd = bid & 7;
    int rest = bid >> 3;           // 0..31
    int bh = xcd * 2 + (rest & 1);
    int nb = rest >> 1;            // 0..15 -> 256 rows each
    int b = bh >> 3, h = bh & 7;

    const short* QT = q   + (size_t)b * N_ * C_ + h * HD_;
    const short* KP = ktp + (size_t)bh * N_ * HD_;
    const short* V  = v   + ((size_t)b * C_ + h * HD_) * N_;
    short* O = aoT + (size_t)b * N_ * C_ + h * HD_;

    __shared__ short kl[2 * 2560];   // K tile: 64 m-rows x 32 d, stride 40
    __shared__ short vl[2 * 2304];   // V tile: 32 d-rows x 64 slots, stride 72 (slot-permuted)

    int tid = threadIdx.x, w = tid >> 6, lane = tid & 63, li = lane & 15, quad = lane >> 4;
    int n0w = nb * 256 + w * 32;     // 8 waves x 32 rows

    short8 qf0 = *(const short8*)&QT[(size_t)(n0w + li) * 256 + quad * 8];
    short8 qf1 = *(const short8*)&QT[(size_t)(n0w + 16 + li) * 256 + quad * 8];

    f32x4 oa00 = (f32x4){0.f,0.f,0.f,0.f}, oa01 = oa00, oa10 = oa00, oa11 = oa00;
    float lr0 = 0.f, lr1 = 0.f;
    const f32x4 zero = (f32x4){0.f, 0.f, 0.f, 0.f};

    int krow = tid >> 3, kcol = (tid & 7) << 2;
    const short* kgp = KP + (size_t)krow * HD_ + kcol;
    int klo = krow * 40 + kcol;
    int vd = tid >> 4, g = tid & 15;
    int mbase = 32 * (g >> 3) + 16 * (g & 1) + 4 * ((g >> 1) & 3);
    const short* vgp = V + (size_t)vd * N_ + mbase;
    int vlo = vd * 72 + g * 4;

    short4v kst = *(const short4v*)kgp;
    short4v vst = *(const short4v*)vgp;

    f32x4 s0[4], s1[4];
    short8 vf[4];

    for (int t = 0; t < 64; ++t) {
        int buf = t & 1;
        *(short4v*)&kl[buf * 2560 + klo] = kst;
        *(short4v*)&vl[buf * 2304 + vlo] = vst;
        if (t < 63) {
            kst = *(const short4v*)(kgp + (size_t)(t + 1) * 64 * HD_);
            vst = *(const short4v*)(vgp + (t + 1) * 64);
        }
        __syncthreads();

        __builtin_amdgcn_s_setprio(1);
#pragma unroll
        for (int c = 0; c < 4; c++) {
            short8 kf = *(short8*)&kl[buf * 2560 + (c * 16 + li) * 40 + quad * 8];
            s0[c] = __builtin_amdgcn_mfma_f32_16x16x32_bf16(kf, qf0, zero, 0, 0, 0);
            s1[c] = __builtin_amdgcn_mfma_f32_16x16x32_bf16(kf, qf1, zero, 0, 0, 0);
        }
        __builtin_amdgcn_s_setprio(0);

        vf[0] = *(short8*)&vl[buf * 2304 + li * 72 + quad * 8];
        vf[1] = *(short8*)&vl[buf * 2304 + (16 + li) * 72 + quad * 8];
        vf[2] = *(short8*)&vl[buf * 2304 + li * 72 + 32 + quad * 8];
        vf[3] = *(short8*)&vl[buf * 2304 + (16 + li) * 72 + 32 + quad * 8];

        unsigned paw[8];
        float lp = 0.f;
#pragma unroll
        for (int c = 0; c < 4; c++) {
            float e0 = __builtin_amdgcn_exp2f(s0[c][0]);
            float e1 = __builtin_amdgcn_exp2f(s0[c][1]);
            float e2 = __builtin_amdgcn_exp2f(s0[c][2]);
            float e3 = __builtin_amdgcn_exp2f(s0[c][3]);
            lp += (e0 + e1) + (e2 + e3);
            paw[2 * c]     = __builtin_amdgcn_perm(__float_as_uint(e1), __float_as_uint(e0), 0x07060302);
            paw[2 * c + 1] = __builtin_amdgcn_perm(__float_as_uint(e3), __float_as_uint(e2), 0x07060302);
        }
        lr0 += lp;
        uint4v p0 = (uint4v){paw[0], paw[1], paw[2], paw[3]};
        uint4v p1 = (uint4v){paw[4], paw[5], paw[6], paw[7]};
        short8 a0 = __builtin_bit_cast(short8, p0);
        short8 a1 = __builtin_bit_cast(short8, p1);

        lp = 0.f;
#pragma unroll
        for (int c = 0; c < 4; c++) {
            float e0 = __builtin_amdgcn_exp2f(s1[c][0]);
            float e1 = __builtin_amdgcn_exp2f(s1[c][1]);
            float e2 = __builtin_amdgcn_exp2f(s1[c][2]);
            float e3 = __builtin_amdgcn_exp2f(s1[c][3]);
            lp += (e0 + e1) + (e2 + e3);
            paw[2 * c]     = __builtin_amdgcn_perm(__float_as_uint(e1), __float_as_uint(e0), 0x07060302);
            paw[2 * c + 1] = __builtin_amdgcn_perm(__float_as_uint(e3), __float_as_uint(e2), 0x07060302);
        }
        lr1 += lp;
        uint4v p2 = (uint4v){paw[0], paw[1], paw[2], paw[3]};
        uint4v p3 = (uint4v){paw[4], paw[5], paw[6], paw[7]};
        short8 a2 = __builtin_bit_cast(short8, p2);
        short8 a3 = __builtin_bit_cast(short8, p3);

        __builtin_amdgcn_s_setprio(1);
        oa00 = __builtin_amdgcn_mfma_f32_16x16x32_bf16(a0, vf[0], oa00, 0, 0, 0);
        oa01 = __builtin_amdgcn_mfma_f32_16x16x32_bf16(a0, vf[1], oa01, 0, 0, 0);
        oa00 = __builtin_amdgcn_mfma_f32_16x16x32_bf16(a1, vf[2], oa00, 0, 0, 0);
        oa01 = __builtin_amdgcn_mfma_f32_16x16x32_bf16(a1, vf[3], oa01, 0, 0, 0);
        oa10 = __builtin_amdgcn_mfma_f32_16x16x32_bf16(a2, vf[0], oa10, 0, 0, 0);
        oa11 = __builtin_amdgcn_mfma_f32_16x16x32_bf16(a2, vf[1], oa11, 0, 0, 0);
        oa10 = __builtin_amdgcn_mfma_f32_16x16x32_bf16(a3, vf[2], oa10, 0, 0, 0);
        oa11 = __builtin_amdgcn_mfma_f32_16x16x32_bf16(a3, vf[3], oa11, 0, 0, 0);
        __builtin_amdgcn_s_setprio(0);
    }

    lr0 += __shfl_xor(lr0, 16); lr0 += __shfl_xor(lr0, 32);
    lr1 += __shfl_xor(lr1, 16); lr1 += __shfl_xor(lr1, 32);
#pragma unroll
    for (int r = 0; r < 4; r++) {
        float ln0 = __shfl(lr0, quad * 4 + r);
        float inv0 = 1.f / ln0;
        size_t n_ = (size_t)(n0w + quad * 4 + r);
        O[n_ * 256 + li]      = f2b(oa00[r] * inv0);
        O[n_ * 256 + 16 + li] = f2b(oa01[r] * inv0);
        float ln1 = __shfl(lr1, quad * 4 + r);
        float inv1 = 1.f / ln1;
        size_t n2 = (size_t)(n0w + 16 + quad * 4 + r);
        O[n2 * 256 + li]      = f2b(oa10[r] * inv1);
        O[n2 * 256 + 16 + li] = f2b(oa11[r] * inv1);
    }
}

// ---------------- Node 4: out projection v3 — full-panel staging, single barrier ----------------
// 512 blocks (2/CU, LDS-capped at 67.6 KB) x 256 threads, 64o x 64n tiles.
// Both 64x256 panels staged ONCE (stride 264 = same 2-way bank profile as [40] layout);
// k-loop is then pure LDS-read + MFMA with zero __syncthreads (was 16 barriers).
__global__ __launch_bounds__(256, 2) void gemm_out(const short* __restrict__ wob,
                                                   const float* __restrict__ bias,
                                                   const short* __restrict__ aoT,
                                                   const float* __restrict__ resid,
                                                   float* __restrict__ out) {
    int b = blockIdx.z;
    const short* X = aoT + (size_t)b * N_ * C_;
    const float* R = resid + (size_t)b * C_ * N_;
    float* outp = out + (size_t)b * C_ * N_;

    __shared__ short wl[64][264];
    __shared__ short xl[64][264];

    int o0 = blockIdx.y * 64, n0 = blockIdx.x * 64;
    int tid = threadIdx.x;
    int w = tid >> 6, lane = tid & 63, li = lane & 15, quad = lane >> 4;
    int wr = w & 1, wc = w >> 1;

    // one-shot staging: 8 short8 chunks/thread per matrix
#pragma unroll
    for (int s = 0; s < 8; s++) {
        int id = tid + 256 * s;
        int row = id >> 5, co = (id & 31) << 3;
        *(short8*)&wl[row][co] = *(const short8*)&wob[(size_t)(o0 + row) * 256 + co];
        *(short8*)&xl[row][co] = *(const short8*)&X[(size_t)(n0 + row) * 256 + co];
    }
    __syncthreads();

    f32x4 acc[2][2];
#pragma unroll
    for (int i = 0; i < 2; i++)
#pragma unroll
        for (int j = 0; j < 2; j++) acc[i][j] = (f32x4){0.f, 0.f, 0.f, 0.f};

#pragma unroll
    for (int k0 = 0; k0 < 256; k0 += 32) {
        short8 af[2], bfr[2];
#pragma unroll
        for (int i = 0; i < 2; i++) af[i]  = *(short8*)&wl[wr * 32 + i * 16 + li][k0 + quad * 8];
#pragma unroll
        for (int j = 0; j < 2; j++) bfr[j] = *(short8*)&xl[wc * 32 + j * 16 + li][k0 + quad * 8];
#pragma unroll
        for (int i = 0; i < 2; i++)
#pragma unroll
            for (int j = 0; j < 2; j++)
                acc[i][j] = __builtin_amdgcn_mfma_f32_16x16x32_bf16(af[i], bfr[j], acc[i][j], 0, 0, 0);
    }

#pragma unroll
    for (int i = 0; i < 2; i++) {
        int ob = o0 + wr * 32 + i * 16 + quad * 4;
#pragma unroll
        for (int j = 0; j < 2; j++) {
            int n_ = n0 + wc * 32 + j * 16 + li;
#pragma unroll
            for (int r = 0; r < 4; r++) {
                size_t idx = (size_t)(ob + r) * N_ + n_;
                outp[idx] = acc[i][j][r] + bias[ob + r] + R[idx];
            }
        }
    }
}

extern "C" void kernel_launch(void* const* d_in, const int* in_sizes, int n_in,
                              void* d_out, int out_size, void* d_ws, size_t ws_size,
                              hipStream_t stream) {
    const float* x  = (const float*)d_in[0];
    const float* gw = (const float*)d_in[1];
    const float* gb = (const float*)d_in[2];
    const float* wq = (const float*)d_in[3];
    const float* bq = (const float*)d_in[4];
    const float* wk = (const float*)d_in[5];
    const float* bk = (const float*)d_in[6];
    const float* wv = (const float*)d_in[7];
    const float* bv = (const float*)d_in[8];
    const float* wo = (const float*)d_in[9];
    const float* bo = (const float*)d_in[10];
    float* out = (float*)d_out;

    char* ws = (char*)d_ws;
    float* part = (float*)ws;                  // 2048 floats
    const size_t TS = (size_t)B_ * N_ * C_;
    short* aoT = (short*)(ws + 16384);         // flash output [b][n][c] bf16 (normalized)
    short* q   = aoT + TS;
    short* kt  = q + TS;                       // packed [b*8+h][m][32]
    short* v   = kt + TS;
    short* wb  = v + TS;                       // bf16 weights [wq|wk|wv|wo], 4*65536 shorts

    prep<<<1152, 256, 0, stream>>>(x, part, wq, wk, wv, wo, wb);
    gemm_qkv<<<dim3(64, 4, 2), 256, 0, stream>>>(x, gw, gb, part, wb,
                                                 bq, bk, bv, q, kt, v);
    flash<<<256, 512, 0, stream>>>(q, kt, v, aoT);
    gemm_out<<<dim3(64, 4, 2), 256, 0, stream>>>(wb + 3 * 65536, bo, aoT, x, out);
}